// Round 13
// baseline (190.229 us; speedup 1.0000x reference)
//
#include <hip/hip_runtime.h>
#include <stdint.h>

#define NPIX 65536
#define IGN (-255)
#define HCAP 512         // pre-filter hit cap per key (mean 256, +16sigma)

// ---------------- threefry2x32 (exact JAX partitionable implementation) ----------------
__device__ __forceinline__ uint32_t rotl32(uint32_t v, uint32_t r){
  return __builtin_amdgcn_alignbit(v, v, 32u - r);
}

__device__ __forceinline__ void tf2x32(uint32_t k0, uint32_t k1, uint32_t x0, uint32_t x1,
                                       uint32_t &o0, uint32_t &o1){
  uint32_t k2 = k0 ^ k1 ^ 0x1BD11BDAu;
  x0 += k0; x1 += k1;
#define TFR(r) { x0 += x1; x1 = rotl32(x1,(r)); x1 ^= x0; }
  TFR(13u) TFR(15u) TFR(26u) TFR(6u)   x0 += k1; x1 += k2 + 1u;
  TFR(17u) TFR(29u) TFR(16u) TFR(24u)  x0 += k2; x1 += k0 + 2u;
  TFR(13u) TFR(15u) TFR(26u) TFR(6u)   x0 += k0; x1 += k1 + 3u;
  TFR(17u) TFR(29u) TFR(16u) TFR(24u)  x0 += k1; x1 += k2 + 4u;
  TFR(13u) TFR(15u) TFR(26u) TFR(6u)   x0 += k2; x1 += k0 + 5u;
#undef TFR
  o0 = x0; o1 = x1;
}

// four independent threefry chains (pixels px..px+3) under ONE fixed key (SGPR operands,
// no per-lane key select). Same algebra as tf2x32 with x0=0, x1=px+i (verified R9-R12).
__device__ __forceinline__ void tf4_fixed(uint32_t K0, uint32_t K1, uint32_t K2,
                                          uint32_t px,
                                          uint32_t &rA, uint32_t &rB,
                                          uint32_t &rC, uint32_t &rD){
  uint32_t a0 = K0, a1 = px + K1;
  uint32_t b0 = K0, b1 = (px + 1u) + K1;
  uint32_t c0 = K0, c1 = (px + 2u) + K1;
  uint32_t d0 = K0, d1 = (px + 3u) + K1;
#define R4(r) { a0 += a1; b0 += b1; c0 += c1; d0 += d1;                       \
  a1 = rotl32(a1,(r)); b1 = rotl32(b1,(r)); c1 = rotl32(c1,(r)); d1 = rotl32(d1,(r)); \
  a1 ^= a0; b1 ^= b0; c1 ^= c0; d1 ^= d0; }
#define I4(K, J, i) { a0 += (K); b0 += (K); c0 += (K); d0 += (K);             \
  a1 += (J) + (i); b1 += (J) + (i); c1 += (J) + (i); d1 += (J) + (i); }
  R4(13u) R4(15u) R4(26u) R4(6u)   I4(K1, K2, 1u)
  R4(17u) R4(29u) R4(16u) R4(24u)  I4(K2, K0, 2u)
  R4(13u) R4(15u) R4(26u) R4(6u)   I4(K0, K1, 3u)
  R4(17u) R4(29u) R4(16u) R4(24u)  I4(K1, K2, 4u)
  R4(13u) R4(15u) R4(26u) R4(6u)   I4(K2, K0, 5u)
#undef R4
#undef I4
  rA = a0 ^ a1; rB = b0 ^ b1; rC = c0 ^ c1; rD = d0 ^ d1;
}

// pack score+index so that u64 max == (higher score, then lower index)
__device__ __forceinline__ unsigned long long packCand(uint32_t bits, uint32_t pix){
  float f = __uint_as_float((bits >> 9) | 0x3f800000u) - 1.0f;  // jax uniform [0,1)
  uint32_t u = __float_as_uint(f) ^ 0x80000000u;                // monotone map (f>=0)
  return ((unsigned long long)u << 32) | (unsigned long long)(0xFFFFFFFFu - pix);
}

// sorted-descending 10-element list, sentinel 0
__device__ __forceinline__ void t10_insert(unsigned long long* l, unsigned long long c){
  if (c > l[9]) {
    l[9] = c;
#pragma unroll
    for (int i = 9; i > 0; --i){
      unsigned long long a = l[i-1], b2 = l[i];
      if (b2 > a){ l[i-1] = b2; l[i] = a; }
    }
  }
}

// ---- single fused kernel, key-split hashing ----
// pass1: read x (4-deep MLP), u8->LDS, hist, AND fg-key hash of every pixel (hidden
// under load latency; hits -> bufF as pix). Barrier. Deferred IGN fill (posted).
// bg-key hash of every pixel (pure ALU, no threshold dep; hits -> bufB). Wave-0
// threshold. Barrier. Region-filter both hit lists (exact counts). Validity.
// Extract (rehash from pix). Merge. Patches.
__global__ __launch_bounds__(1024)
void apm_kernel(const float* __restrict__ x, int* __restrict__ out){
  const int b = blockIdx.x;
  const int tid = threadIdx.x;
  const float* img = x + (size_t)b * NPIX;
  int* outb = out + (size_t)b * NPIX;

  __shared__ uint32_t u8img[16384];         // 64 KB: packed u8 image (4 px/word)
  __shared__ uint32_t histR[1024];          // 256 bins x 4 lane-columns
  __shared__ float csum[256], cvsum[256];
  __shared__ uint32_t s_kw[4];
  __shared__ int bufF[HCAP], bufB[HCAP];    // hit pixel indices (pre/post filter)
  __shared__ int s_hc[2], s_cc[2], s_fail[2], s_np[2];
  __shared__ int s_qthr, s_nroi;
  __shared__ unsigned long long s_top[2][64][10];
  __shared__ unsigned long long s_top2[2][8][10];
  __shared__ int s_pr[2][10], s_pc[2][10];

  histR[tid] = 0u;
  if (tid < 2){
    uint32_t o0, o1;
    tf2x32(0u, 1u, 0u, (uint32_t)(2*b + tid), o0, o1);
    s_kw[2*tid] = o0; s_kw[2*tid+1] = o1;
    s_hc[tid] = 0; s_cc[tid] = 0;
  }
  __syncthreads();

  const uint32_t fk0 = s_kw[0], fk1 = s_kw[1], bk0 = s_kw[2], bk1 = s_kw[3];
  const uint32_t fk2 = fk0 ^ fk1 ^ 0x1BD11BDAu;
  const uint32_t bk2 = bk0 ^ bk1 ^ 0x1BD11BDAu;

  // ---- pass 1: 4-deep batched loads, u8->LDS, hist, fg-key hash of all pixels ----
  {
    const float4* x4 = (const float4*)img;
    const uint32_t c4 = (uint32_t)(tid & 3);
#define PROC(V, K) {                                                          \
      uint32_t u0 = (uint32_t)min(max((int)floorf((V).x*255.0f),0),255);      \
      uint32_t u1 = (uint32_t)min(max((int)floorf((V).y*255.0f),0),255);      \
      uint32_t u2 = (uint32_t)min(max((int)floorf((V).z*255.0f),0),255);      \
      uint32_t u3 = (uint32_t)min(max((int)floorf((V).w*255.0f),0),255);      \
      u8img[tid + 1024*(K)] = u0 | (u1<<8) | (u2<<16) | (u3<<24);             \
      atomicAdd(&histR[(u0<<2)|c4],1u); atomicAdd(&histR[(u1<<2)|c4],1u);     \
      atomicAdd(&histR[(u2<<2)|c4],1u); atomicAdd(&histR[(u3<<2)|c4],1u);     \
      uint32_t pb = (uint32_t)(4*(tid + 1024*(K)));                           \
      uint32_t hA,hB,hC,hD;                                                   \
      tf4_fixed(fk0,fk1,fk2, pb, hA,hB,hC,hD);                                \
      if (hA >= 0xFF000000u){ int i2=atomicAdd(&s_hc[0],1); if(i2<HCAP) bufF[i2]=(int)pb; }      \
      if (hB >= 0xFF000000u){ int i2=atomicAdd(&s_hc[0],1); if(i2<HCAP) bufF[i2]=(int)(pb+1u); } \
      if (hC >= 0xFF000000u){ int i2=atomicAdd(&s_hc[0],1); if(i2<HCAP) bufF[i2]=(int)(pb+2u); } \
      if (hD >= 0xFF000000u){ int i2=atomicAdd(&s_hc[0],1); if(i2<HCAP) bufF[i2]=(int)(pb+3u); } }
    for (int kk = 0; kk < 4; ++kk){         // 4 x 4 x 1024 = 16384 float4 = 65536 px
      int base = 4*kk;
      float4 v0 = x4[tid + 1024*(base+0)];
      float4 v1 = x4[tid + 1024*(base+1)];
      float4 v2 = x4[tid + 1024*(base+2)];
      float4 v3 = x4[tid + 1024*(base+3)];
      PROC(v0, base+0) PROC(v1, base+1) PROC(v2, base+2) PROC(v3, base+3)
    }
#undef PROC
  }
  __syncthreads();

  // ---- deferred IGN fill: posted stores drain under the bg-hash phase below ----
  {
    int4* o4 = (int4*)outb;
    const int4 f4 = make_int4(IGN, IGN, IGN, IGN);
#pragma unroll
    for (int k = 0; k < 16; ++k) o4[tid + 1024*k] = f4;
  }

  // ---- bg-key hash of all pixels: pure ALU, no memory, no threshold dependency ----
  for (int k = 0; k < 16; ++k){
    uint32_t pb = (uint32_t)(4*(tid + 1024*k));
    uint32_t hA,hB,hC,hD;
    tf4_fixed(bk0,bk1,bk2, pb, hA,hB,hC,hD);
    if (hA >= 0xFF000000u){ int i2=atomicAdd(&s_hc[1],1); if(i2<HCAP) bufB[i2]=(int)pb; }
    if (hB >= 0xFF000000u){ int i2=atomicAdd(&s_hc[1],1); if(i2<HCAP) bufB[i2]=(int)(pb+1u); }
    if (hC >= 0xFF000000u){ int i2=atomicAdd(&s_hc[1],1); if(i2<HCAP) bufB[i2]=(int)(pb+2u); }
    if (hD >= 0xFF000000u){ int i2=atomicAdd(&s_hc[1],1); if(i2<HCAP) bufB[i2]=(int)(pb+3u); }
  }

  // ---- threshold: wave 0 only, shuffle-based (verified R7-R12 structure) ----
  // exactness: all partial sums are integers < 2^24 -> fp32 adds in any order
  // are bit-identical to jnp.cumsum.
  if (tid < 64){
    const int lane = tid;
    const int4* hv = (const int4*)&histR[16*lane];
    int4 p0 = hv[0], p1 = hv[1], p2 = hv[2], p3 = hv[3];
    int h0 = p0.x + p0.y + p0.z + p0.w;
    int h1 = p1.x + p1.y + p1.z + p1.w;
    int h2 = p2.x + p2.y + p2.z + p2.w;
    int h3 = p3.x + p3.y + p3.z + p3.w;
    int cand = 256;
    if (h3) cand = 4*lane + 3;
    if (h2) cand = 4*lane + 2;
    if (h1) cand = 4*lane + 1;
    if (h0) cand = 4*lane + 0;
    for (int off = 32; off; off >>= 1) cand = min(cand, __shfl_xor(cand, off));
    const float img_min = (float)cand;
    float c0 = (float)h0, c1 = c0 + h1, c2 = c1 + h2, c3 = c2 + h3;
    float bv = 4.0f*lane - img_min;
    float v0 = h0*bv;
    float v1 = v0 + h1*(bv + 1.0f);
    float v2 = v1 + h2*(bv + 2.0f);
    float v3 = v2 + h3*(bv + 3.0f);
    float cc = c3, vv = v3;
    for (int off = 1; off < 64; off <<= 1){
      float a = __shfl_up(cc, off), b2 = __shfl_up(vv, off);
      if (lane >= off){ cc += a; vv += b2; }
    }
    const float cexc = cc - c3, vexc = vv - v3;
    const float cs0 = cexc+c0, cs1 = cexc+c1, cs2 = cexc+c2, cs3 = cexc+c3;
    const float vs0 = vexc+v0, vs1 = vexc+v1, vs2 = vexc+v2, vs3 = vexc+v3;
    csum[4*lane]   = cs0; csum[4*lane+1]  = cs1;
    csum[4*lane+2] = cs2; csum[4*lane+3]  = cs3;
    cvsum[4*lane]   = vs0; cvsum[4*lane+1] = vs1;
    cvsum[4*lane+2] = vs2; cvsum[4*lane+3] = vs3;
    const float ctot = __shfl(cc, 63), vtot = __shfl(vv, 63);
    const float s_tot_o = vtot + img_min * ctot;
    unsigned long long best = 0ull;
#define OTSU_BIN(CS, VS, J)                                              \
    { int bin = 4*lane + (J);                                            \
      if (bin < 255){                                                    \
        float w0_ = (CS);                                                \
        float w1_ = 65536.0f - w0_;                                      \
        float cs = (VS) + img_min * (CS);                                \
        float m0 = cs / fmaxf(w0_, 1e-12f);                              \
        float m1 = (s_tot_o - cs) / fmaxf(w1_, 1e-12f);                  \
        float d = m0 - m1;                                               \
        float vb = (w0_*w1_) * (d*d);                                    \
        unsigned long long pk =                                          \
          ((unsigned long long)__float_as_uint(vb) << 32) |              \
           (unsigned long long)(255 - bin);                              \
        if (pk > best) best = pk;                                        \
      } }
    OTSU_BIN(cs0, vs0, 0) OTSU_BIN(cs1, vs1, 1)
    OTSU_BIN(cs2, vs2, 2) OTSU_BIN(cs3, vs3, 3)
#undef OTSU_BIN
    for (int off = 32; off; off >>= 1){
      unsigned int hi = (unsigned int)(best >> 32), lo = (unsigned int)best;
      unsigned int hio = (unsigned int)__shfl_xor((int)hi, off);
      unsigned int loo = (unsigned int)__shfl_xor((int)lo, off);
      unsigned long long ob = ((unsigned long long)hio << 32) | loo;
      if (ob > best) best = ob;
    }
    if (lane == 0){
      int bestIdx = 255 - (int)(best & 0xFFFFFFFFull);
      float otsu = fminf(fmaxf((float)bestIdx, 1.0f), 254.0f);
      float n_tot = ctot, s_tot = vtot;
      float t_curr = otsu - img_min, t_prev = t_curr + 10.0f;
      int it = 0;
      while (fabsf(t_curr - t_prev) > 0.5f && it < 64){
        int idx = min(max((int)floorf(t_curr + img_min), 0), 255);
        float n_back = csum[idx], s_back = cvsum[idx];
        float n_fore = n_tot - n_back, s_fore = s_tot - s_back;
        float mean_back = (n_back > 0.0f) ? (s_back / fmaxf(n_back, 1.0f)) : 0.0f;
        float mean_fore = s_fore / fmaxf(n_fore, 1.0f);
        float t_next = (mean_back - mean_fore) /
                       (logf(fmaxf(mean_back, 1e-12f)) - logf(fmaxf(mean_fore, 1e-12f)));
        if (mean_back < 1e-12f) t_next = mean_fore * 0.5f;
        t_prev = t_curr; t_curr = t_next; ++it;
      }
      float lit = t_curr + img_min;
      // integer threshold: for integer q, (float)q > lit <=> q >= floor(lit)+1
      // NaN lit (degenerate image): predicate false for all q -> qthr=256
      int qthr;
      if (!(lit == lit)) qthr = 256;
      else               qthr = (int)floorf(lit) + 1;
      s_qthr = qthr;
      int nlo = (qthr <= 0) ? 0 : (int)csum[min(qthr, 256) - 1];
      s_nroi = NPIX - nlo;             // exact count(q > lit)
    }
  }
  __syncthreads();

  // ---- region-filter both hit lists (in-place compact, exact counts) ----
  const int qthr = s_qthr;
  {
    int rawF = min(s_hc[0], HCAP), rawB = min(s_hc[1], HCAP);
    int pF = -1, pB = -1;
    if (tid < rawF) pF = bufF[tid];
    if (tid < rawB) pB = bufB[tid];
    bool kF = (pF >= 0) &&
      ((int)((u8img[(uint32_t)pF >> 2] >> (8*((uint32_t)pF & 3u))) & 255u) >= qthr);
    bool kB = (pB >= 0) &&
      ((int)((u8img[(uint32_t)pB >> 2] >> (8*((uint32_t)pB & 3u))) & 255u) <  qthr);
    __syncthreads();
    if (kF){ int i2 = atomicAdd(&s_cc[0], 1); bufF[i2] = pF; }
    if (kB){ int i2 = atomicAdd(&s_cc[1], 1); bufB[i2] = pB; }
  }
  __syncthreads();

  // ---- validity: overflow of raw hit list OR (cc<10 && cc != region size) ----
  if (tid < 2){
    int rs = tid ? (NPIX - s_nroi) : s_nroi;
    s_fail[tid] = (s_hc[tid] > HCAP) || (s_cc[tid] < 10 && s_cc[tid] != rs);
  }
  __syncthreads();

  // ---- per-lane top-10 (wave 0 -> fg, wave 1 -> bg); rehash from pix; fallback scans ----
  const int wv = tid >> 6, lane = tid & 63;
  if (wv < 2){
    const int r2 = wv;
    unsigned long long t[10];
#pragma unroll
    for (int i = 0; i < 10; ++i) t[i] = 0ull;
    const uint32_t kk0 = s_kw[2*r2], kk1 = s_kw[2*r2+1];
    if (!s_fail[r2]){
      int n = s_cc[r2];
      const int* cl = r2 ? bufB : bufF;
      for (int i = lane; i < n; i += 64){
        uint32_t pix = (uint32_t)cl[i];
        uint32_t o0, o1; tf2x32(kk0, kk1, 0u, pix, o0, o1);
        t10_insert(t, packCand(o0 ^ o1, pix));
      }
    } else {
      for (int k = 0; k < 1024; ++k){
        uint32_t pix = (uint32_t)(lane + 64*k);
        int q = (int)((u8img[pix >> 2] >> (8*(pix & 3u))) & 255u);
        bool r = (q >= qthr);
        if (r == (r2 == 0)){
          uint32_t o0, o1; tf2x32(kk0, kk1, 0u, pix, o0, o1);
          t10_insert(t, packCand(o0 ^ o1, pix));
        }
      }
    }
#pragma unroll
    for (int i = 0; i < 10; ++i) s_top[r2][lane][i] = t[i];
  }
  __syncthreads();
  // ---- merge 64 -> 8 ----
  if (wv < 2 && lane < 8){
    unsigned long long t[10];
#pragma unroll
    for (int i = 0; i < 10; ++i) t[i] = 0ull;
    for (int l2 = 0; l2 < 8; ++l2)
#pragma unroll
      for (int i = 0; i < 10; ++i) t10_insert(t, s_top[wv][lane*8 + l2][i]);
#pragma unroll
    for (int i = 0; i < 10; ++i) s_top2[wv][lane][i] = t[i];
  }
  __syncthreads();
  // ---- merge 8 -> 1, extract points ----
  if (wv < 2 && lane == 0){
    unsigned long long t[10];
#pragma unroll
    for (int i = 0; i < 10; ++i) t[i] = 0ull;
    for (int l2 = 0; l2 < 8; ++l2)
#pragma unroll
      for (int i = 0; i < 10; ++i) t10_insert(t, s_top2[wv][l2][i]);
    int np = 0;
    for (int i = 0; i < 10; ++i){
      if (t[i]){
        uint32_t pix = 0xFFFFFFFFu - (uint32_t)(t[i] & 0xFFFFFFFFull);
        s_pr[wv][np] = (int)(pix >> 8);
        s_pc[wv][np] = (int)(pix & 255u);
        ++np;
      }
    }
    s_np[wv] = np;
  }
  __syncthreads();

  // ---- write dilated seed patches (<=180 px); duplicates write identical values ----
  const int nfg = s_np[0], nbg = s_np[1];
  const int npts = nfg + nbg;
  if (tid < npts*9){
    int k = tid / 9, d = tid - k*9;
    int pr = (k < nfg) ? s_pr[0][k] : s_pr[1][k - nfg];
    int pc = (k < nfg) ? s_pc[0][k] : s_pc[1][k - nfg];
    pr += d/3 - 1; pc += d%3 - 1;
    if (pr >= 0 && pr < 256 && pc >= 0 && pc < 256){
      bool fgd = false, bgd = false;
      for (int i = 0; i < nfg; ++i) fgd |= (abs(pr - s_pr[0][i]) <= 1) && (abs(pc - s_pc[0][i]) <= 1);
      for (int i = 0; i < nbg; ++i) bgd |= (abs(pr - s_pr[1][i]) <= 1) && (abs(pc - s_pc[1][i]) <= 1);
      int val = (fgd && bgd) ? IGN : (fgd ? 1 : 0);
      outb[pr*256 + pc] = val;
    }
  }
}

extern "C" void kernel_launch(void* const* d_in, const int* in_sizes, int n_in,
                              void* d_out, int out_size, void* d_ws, size_t ws_size,
                              hipStream_t stream) {
  const float* x = (const float*)d_in[0];
  int* out = (int*)d_out;
  int B = in_sizes[0] / NPIX;
  apm_kernel<<<B, 1024, 0, stream>>>(x, out);
}

// Round 14
// 186.899 us; speedup vs baseline: 1.0178x; 1.0178x over previous
//
#include <hip/hip_runtime.h>
#include <stdint.h>

#define NPIX 65536
#define IGN (-255)
#define CAP 768          // LDS candidate list capacity per region (mean ~128, +32sigma)

// ---------------- threefry2x32 (exact JAX partitionable implementation) ----------------
__device__ __forceinline__ uint32_t rotl32(uint32_t v, uint32_t r){
  return __builtin_amdgcn_alignbit(v, v, 32u - r);
}

__device__ __forceinline__ void tf2x32(uint32_t k0, uint32_t k1, uint32_t x0, uint32_t x1,
                                       uint32_t &o0, uint32_t &o1){
  uint32_t k2 = k0 ^ k1 ^ 0x1BD11BDAu;
  x0 += k0; x1 += k1;
#define TFR(r) { x0 += x1; x1 = rotl32(x1,(r)); x1 ^= x0; }
  TFR(13u) TFR(15u) TFR(26u) TFR(6u)   x0 += k1; x1 += k2 + 1u;
  TFR(17u) TFR(29u) TFR(16u) TFR(24u)  x0 += k2; x1 += k0 + 2u;
  TFR(13u) TFR(15u) TFR(26u) TFR(6u)   x0 += k0; x1 += k1 + 3u;
  TFR(17u) TFR(29u) TFR(16u) TFR(24u)  x0 += k1; x1 += k2 + 4u;
  TFR(13u) TFR(15u) TFR(26u) TFR(6u)   x0 += k2; x1 += k0 + 5u;
#undef TFR
  o0 = x0; o1 = x1;
}

// four independent threefry chains (pixels px..px+3), source-interleaved (verified R12).
__device__ __forceinline__ void tf4_quad(
  uint32_t A0, uint32_t A1, uint32_t A2,
  uint32_t B0, uint32_t B1, uint32_t B2,
  uint32_t C0, uint32_t C1, uint32_t C2,
  uint32_t D0, uint32_t D1, uint32_t D2,
  uint32_t px,
  uint32_t &rA, uint32_t &rB, uint32_t &rC, uint32_t &rD)
{
  uint32_t a0 = A0, a1 = px + A1;
  uint32_t b0 = B0, b1 = (px + 1u) + B1;
  uint32_t c0 = C0, c1 = (px + 2u) + C1;
  uint32_t d0 = D0, d1 = (px + 3u) + D1;
#define R4(r) { a0 += a1; b0 += b1; c0 += c1; d0 += d1;                       \
  a1 = rotl32(a1,(r)); b1 = rotl32(b1,(r)); c1 = rotl32(c1,(r)); d1 = rotl32(d1,(r)); \
  a1 ^= a0; b1 ^= b0; c1 ^= c0; d1 ^= d0; }
#define INJ4(KA,KB,KC,KD, JA,JB,JC,JD, i) {                                   \
  a0 += (KA); b0 += (KB); c0 += (KC); d0 += (KD);                             \
  a1 += (JA) + (i); b1 += (JB) + (i); c1 += (JC) + (i); d1 += (JD) + (i); }
  R4(13u) R4(15u) R4(26u) R4(6u)
  INJ4(A1,B1,C1,D1, A2,B2,C2,D2, 1u)
  R4(17u) R4(29u) R4(16u) R4(24u)
  INJ4(A2,B2,C2,D2, A0,B0,C0,D0, 2u)
  R4(13u) R4(15u) R4(26u) R4(6u)
  INJ4(A0,B0,C0,D0, A1,B1,C1,D1, 3u)
  R4(17u) R4(29u) R4(16u) R4(24u)
  INJ4(A1,B1,C1,D1, A2,B2,C2,D2, 4u)
  R4(13u) R4(15u) R4(26u) R4(6u)
  INJ4(A2,B2,C2,D2, A0,B0,C0,D0, 5u)
#undef R4
#undef INJ4
  rA = a0 ^ a1; rB = b0 ^ b1; rC = c0 ^ c1; rD = d0 ^ d1;
}

// pack score+index so that u64 max == (higher score, then lower index)
__device__ __forceinline__ unsigned long long packCand(uint32_t bits, uint32_t pix){
  float f = __uint_as_float((bits >> 9) | 0x3f800000u) - 1.0f;  // jax uniform [0,1)
  uint32_t u = __float_as_uint(f) ^ 0x80000000u;                // monotone map (f>=0)
  return ((unsigned long long)u << 32) | (unsigned long long)(0xFFFFFFFFu - pix);
}

// sorted-descending 10-element list, sentinel 0
__device__ __forceinline__ void t10_insert(unsigned long long* l, unsigned long long c){
  if (c > l[9]) {
    l[9] = c;
#pragma unroll
    for (int i = 9; i > 0; --i){
      unsigned long long a = l[i-1], b2 = l[i];
      if (b2 > a){ l[i-1] = b2; l[i] = a; }
    }
  }
}

// ---- single fused kernel (no LDS image) ----
// pass1: read x (4-deep MLP) -> histogram only. Threshold (wave-0 shuffle).
// Deferred IGN fill (drains under scoring). Scoring re-reads x from L3, quantizes
// inline, 4-way-ILP threefry. Wave-parallel top-10. Dilated patches.
__global__ __launch_bounds__(1024)
void apm_kernel(const float* __restrict__ x, int* __restrict__ out){
  const int b = blockIdx.x;
  const int tid = threadIdx.x;
  const float* img = x + (size_t)b * NPIX;
  int* outb = out + (size_t)b * NPIX;

  __shared__ uint32_t histR[1024];          // 256 bins x 4 lane-columns (conflict spread)
  __shared__ float csum[256], cvsum[256];
  __shared__ uint32_t s_kw[4];
  __shared__ unsigned long long buf[2][CAP];
  __shared__ int s_cnt[2], s_fail[2], s_np[2];
  __shared__ int s_qthr, s_nroi;
  __shared__ unsigned long long s_top[2][64][10];
  __shared__ unsigned long long s_top2[2][8][10];
  __shared__ int s_pr[2][10], s_pc[2][10];

  histR[tid] = 0u;
  if (tid < 2){
    uint32_t o0, o1;
    tf2x32(0u, 1u, 0u, (uint32_t)(2*b + tid), o0, o1);
    s_kw[2*tid] = o0; s_kw[2*tid+1] = o1;
    s_cnt[tid] = 0;
  }
  __syncthreads();

  // ---- pass 1: 4-deep batched float4 loads, histogram only ----
  {
    const float4* x4 = (const float4*)img;
    const uint32_t c4 = (uint32_t)(tid & 3);
#define PROC(V) {                                                             \
      uint32_t u0 = (uint32_t)min(max((int)floorf((V).x*255.0f),0),255);      \
      uint32_t u1 = (uint32_t)min(max((int)floorf((V).y*255.0f),0),255);      \
      uint32_t u2 = (uint32_t)min(max((int)floorf((V).z*255.0f),0),255);      \
      uint32_t u3 = (uint32_t)min(max((int)floorf((V).w*255.0f),0),255);      \
      atomicAdd(&histR[(u0<<2)|c4],1u); atomicAdd(&histR[(u1<<2)|c4],1u);     \
      atomicAdd(&histR[(u2<<2)|c4],1u); atomicAdd(&histR[(u3<<2)|c4],1u); }
    for (int kk = 0; kk < 4; ++kk){         // 4 x 4 x 1024 = 16384 float4 = 65536 px
      int base = 4*kk;
      float4 v0 = x4[tid + 1024*(base+0)];
      float4 v1 = x4[tid + 1024*(base+1)];
      float4 v2 = x4[tid + 1024*(base+2)];
      float4 v3 = x4[tid + 1024*(base+3)];
      PROC(v0) PROC(v1) PROC(v2) PROC(v3)
    }
#undef PROC
  }
  __syncthreads();

  // ---- threshold: wave 0 only, shuffle-based (verified R7-R12 structure) ----
  // exactness: all partial sums are integers < 2^24 -> fp32 adds in any order
  // are bit-identical to jnp.cumsum.
  if (tid < 64){
    const int lane = tid;
    const int4* hv = (const int4*)&histR[16*lane];  // bins 4lane..4lane+3, 4 cols each
    int4 p0 = hv[0], p1 = hv[1], p2 = hv[2], p3 = hv[3];
    int h0 = p0.x + p0.y + p0.z + p0.w;
    int h1 = p1.x + p1.y + p1.z + p1.w;
    int h2 = p2.x + p2.y + p2.z + p2.w;
    int h3 = p3.x + p3.y + p3.z + p3.w;
    int cand = 256;
    if (h3) cand = 4*lane + 3;
    if (h2) cand = 4*lane + 2;
    if (h1) cand = 4*lane + 1;
    if (h0) cand = 4*lane + 0;
    for (int off = 32; off; off >>= 1) cand = min(cand, __shfl_xor(cand, off));
    const float img_min = (float)cand;
    float c0 = (float)h0, c1 = c0 + h1, c2 = c1 + h2, c3 = c2 + h3;
    float bv = 4.0f*lane - img_min;
    float v0 = h0*bv;
    float v1 = v0 + h1*(bv + 1.0f);
    float v2 = v1 + h2*(bv + 2.0f);
    float v3 = v2 + h3*(bv + 3.0f);
    float cc = c3, vv = v3;
    for (int off = 1; off < 64; off <<= 1){
      float a = __shfl_up(cc, off), b2 = __shfl_up(vv, off);
      if (lane >= off){ cc += a; vv += b2; }
    }
    const float cexc = cc - c3, vexc = vv - v3;
    const float cs0 = cexc+c0, cs1 = cexc+c1, cs2 = cexc+c2, cs3 = cexc+c3;
    const float vs0 = vexc+v0, vs1 = vexc+v1, vs2 = vexc+v2, vs3 = vexc+v3;
    csum[4*lane]   = cs0; csum[4*lane+1]  = cs1;
    csum[4*lane+2] = cs2; csum[4*lane+3]  = cs3;
    cvsum[4*lane]   = vs0; cvsum[4*lane+1] = vs1;
    cvsum[4*lane+2] = vs2; cvsum[4*lane+3] = vs3;
    const float ctot = __shfl(cc, 63), vtot = __shfl(vv, 63);
    const float s_tot_o = vtot + img_min * ctot;
    unsigned long long best = 0ull;
#define OTSU_BIN(CS, VS, J)                                              \
    { int bin = 4*lane + (J);                                            \
      if (bin < 255){                                                    \
        float w0_ = (CS);                                                \
        float w1_ = 65536.0f - w0_;                                      \
        float cs = (VS) + img_min * (CS);                                \
        float m0 = cs / fmaxf(w0_, 1e-12f);                              \
        float m1 = (s_tot_o - cs) / fmaxf(w1_, 1e-12f);                  \
        float d = m0 - m1;                                               \
        float vb = (w0_*w1_) * (d*d);                                    \
        unsigned long long pk =                                          \
          ((unsigned long long)__float_as_uint(vb) << 32) |              \
           (unsigned long long)(255 - bin);                              \
        if (pk > best) best = pk;                                        \
      } }
    OTSU_BIN(cs0, vs0, 0) OTSU_BIN(cs1, vs1, 1)
    OTSU_BIN(cs2, vs2, 2) OTSU_BIN(cs3, vs3, 3)
#undef OTSU_BIN
    for (int off = 32; off; off >>= 1){
      unsigned int hi = (unsigned int)(best >> 32), lo = (unsigned int)best;
      unsigned int hio = (unsigned int)__shfl_xor((int)hi, off);
      unsigned int loo = (unsigned int)__shfl_xor((int)lo, off);
      unsigned long long ob = ((unsigned long long)hio << 32) | loo;
      if (ob > best) best = ob;
    }
    if (lane == 0){
      int bestIdx = 255 - (int)(best & 0xFFFFFFFFull);
      float otsu = fminf(fmaxf((float)bestIdx, 1.0f), 254.0f);
      float n_tot = ctot, s_tot = vtot;
      float t_curr = otsu - img_min, t_prev = t_curr + 10.0f;
      int it = 0;
      while (fabsf(t_curr - t_prev) > 0.5f && it < 64){
        int idx = min(max((int)floorf(t_curr + img_min), 0), 255);
        float n_back = csum[idx], s_back = cvsum[idx];
        float n_fore = n_tot - n_back, s_fore = s_tot - s_back;
        float mean_back = (n_back > 0.0f) ? (s_back / fmaxf(n_back, 1.0f)) : 0.0f;
        float mean_fore = s_fore / fmaxf(n_fore, 1.0f);
        float t_next = (mean_back - mean_fore) /
                       (logf(fmaxf(mean_back, 1e-12f)) - logf(fmaxf(mean_fore, 1e-12f)));
        if (mean_back < 1e-12f) t_next = mean_fore * 0.5f;
        t_prev = t_curr; t_curr = t_next; ++it;
      }
      float lit = t_curr + img_min;
      // integer threshold: for integer q, (float)q > lit <=> q >= floor(lit)+1
      // NaN lit (degenerate image): predicate false for all q -> qthr=256
      int qthr;
      if (!(lit == lit)) qthr = 256;
      else               qthr = (int)floorf(lit) + 1;
      s_qthr = qthr;
      int nlo = (qthr <= 0) ? 0 : (int)csum[min(qthr, 256) - 1];
      s_nroi = NPIX - nlo;             // exact count(q > lit)
    }
  }
  __syncthreads();

  // ---- deferred IGN fill: posted stores drain under the scoring phase below ----
  {
    int4* o4 = (int4*)outb;
    const int4 f4 = make_int4(IGN, IGN, IGN, IGN);
#pragma unroll
    for (int k = 0; k < 16; ++k) o4[tid + 1024*k] = f4;
  }

  // ---- scoring: re-read x from L3, inline quantize, 4 chains per word (4-way ILP) ----
  const int qthr = s_qthr;
  const uint32_t fk0 = s_kw[0], fk1 = s_kw[1], bk0 = s_kw[2], bk1 = s_kw[3];
  const uint32_t fk2 = fk0 ^ fk1 ^ 0x1BD11BDAu;
  const uint32_t bk2 = bk0 ^ bk1 ^ 0x1BD11BDAu;
  {
    const float4* x4 = (const float4*)img;
    for (int k = 0; k < 16; ++k){           // runtime loop: body I$-resident
      float4 v = x4[tid + 1024*k];
      uint32_t pb = (uint32_t)(4*(tid + 1024*k));
      int q0 = min(max((int)floorf(v.x*255.0f),0),255);
      int q1 = min(max((int)floorf(v.y*255.0f),0),255);
      int q2 = min(max((int)floorf(v.z*255.0f),0),255);
      int q3 = min(max((int)floorf(v.w*255.0f),0),255);
      bool r0 = (q0 >= qthr), r1 = (q1 >= qthr), r2 = (q2 >= qthr), r3 = (q3 >= qthr);
      uint32_t bA, bB, bC, bD;
      tf4_quad(r0?fk0:bk0, r0?fk1:bk1, r0?fk2:bk2,
               r1?fk0:bk0, r1?fk1:bk1, r1?fk2:bk2,
               r2?fk0:bk0, r2?fk1:bk1, r2?fk2:bk2,
               r3?fk0:bk0, r3?fk1:bk1, r3?fk2:bk2,
               pb, bA, bB, bC, bD);
#define HIT(BITS, RR, PIX) if ((BITS) >= 0xFF000000u){                        \
        int r2_ = (RR) ? 0 : 1;                                               \
        int idx = atomicAdd(&s_cnt[r2_], 1);                                  \
        if (idx < CAP) buf[r2_][idx] = packCand((BITS), (PIX)); }
      HIT(bA, r0, pb)
      HIT(bB, r1, pb + 1u)
      HIT(bC, r2, pb + 2u)
      HIT(bD, r3, pb + 3u)
#undef HIT
    }
  }
  __syncthreads();

  // ---- validity: need (collected >= 10) or (collected == region size); no overflow ----
  if (tid < 2){
    int rs = tid ? (NPIX - s_nroi) : s_nroi;
    int cc = s_cnt[tid];
    s_fail[tid] = (cc > CAP) || (cc < 10 && cc != rs);
  }
  __syncthreads();

  // ---- per-lane top-10 (wave 0 -> fg, wave 1 -> bg); fallback rescans floats ----
  const int wv = tid >> 6, lane = tid & 63;
  if (wv < 2){
    const int r2 = wv;
    unsigned long long t[10];
#pragma unroll
    for (int i = 0; i < 10; ++i) t[i] = 0ull;
    if (!s_fail[r2]){
      int n = min(s_cnt[r2], CAP);
      for (int i = lane; i < n; i += 64) t10_insert(t, buf[r2][i]);
    } else {
      const uint32_t kk0 = s_kw[2*r2], kk1 = s_kw[2*r2+1];
      for (int k = 0; k < 1024; ++k){
        uint32_t pix = (uint32_t)(lane + 64*k);
        float vv2 = img[pix];
        int q = min(max((int)floorf(vv2*255.0f),0),255);
        bool r = (q >= qthr);
        if (r == (r2 == 0)){
          uint32_t o0, o1; tf2x32(kk0, kk1, 0u, pix, o0, o1);
          t10_insert(t, packCand(o0 ^ o1, pix));
        }
      }
    }
#pragma unroll
    for (int i = 0; i < 10; ++i) s_top[r2][lane][i] = t[i];
  }
  __syncthreads();
  // ---- merge 64 -> 8 ----
  if (wv < 2 && lane < 8){
    unsigned long long t[10];
#pragma unroll
    for (int i = 0; i < 10; ++i) t[i] = 0ull;
    for (int l2 = 0; l2 < 8; ++l2)
#pragma unroll
      for (int i = 0; i < 10; ++i) t10_insert(t, s_top[wv][lane*8 + l2][i]);
#pragma unroll
    for (int i = 0; i < 10; ++i) s_top2[wv][lane][i] = t[i];
  }
  __syncthreads();
  // ---- merge 8 -> 1, extract points ----
  if (wv < 2 && lane == 0){
    unsigned long long t[10];
#pragma unroll
    for (int i = 0; i < 10; ++i) t[i] = 0ull;
    for (int l2 = 0; l2 < 8; ++l2)
#pragma unroll
      for (int i = 0; i < 10; ++i) t10_insert(t, s_top2[wv][l2][i]);
    int np = 0;
    for (int i = 0; i < 10; ++i){
      if (t[i]){
        uint32_t pix = 0xFFFFFFFFu - (uint32_t)(t[i] & 0xFFFFFFFFull);
        s_pr[wv][np] = (int)(pix >> 8);
        s_pc[wv][np] = (int)(pix & 255u);
        ++np;
      }
    }
    s_np[wv] = np;
  }
  __syncthreads();

  // ---- write dilated seed patches (<=180 px); duplicates write identical values ----
  const int nfg = s_np[0], nbg = s_np[1];
  const int npts = nfg + nbg;
  if (tid < npts*9){
    int k = tid / 9, d = tid - k*9;
    int pr = (k < nfg) ? s_pr[0][k] : s_pr[1][k - nfg];
    int pc = (k < nfg) ? s_pc[0][k] : s_pc[1][k - nfg];
    pr += d/3 - 1; pc += d%3 - 1;
    if (pr >= 0 && pr < 256 && pc >= 0 && pc < 256){
      bool fgd = false, bgd = false;
      for (int i = 0; i < nfg; ++i) fgd |= (abs(pr - s_pr[0][i]) <= 1) && (abs(pc - s_pc[0][i]) <= 1);
      for (int i = 0; i < nbg; ++i) bgd |= (abs(pr - s_pr[1][i]) <= 1) && (abs(pc - s_pc[1][i]) <= 1);
      int val = (fgd && bgd) ? IGN : (fgd ? 1 : 0);
      outb[pr*256 + pc] = val;
    }
  }
}

extern "C" void kernel_launch(void* const* d_in, const int* in_sizes, int n_in,
                              void* d_out, int out_size, void* d_ws, size_t ws_size,
                              hipStream_t stream) {
  const float* x = (const float*)d_in[0];
  int* out = (int*)d_out;
  int B = in_sizes[0] / NPIX;
  apm_kernel<<<B, 1024, 0, stream>>>(x, out);
}

// Round 15
// 163.455 us; speedup vs baseline: 1.1638x; 1.1434x over previous
//
#include <hip/hip_runtime.h>
#include <stdint.h>

#define NPIX 65536
#define IGN (-255)
#define CAP 768          // LDS candidate list capacity per region (mean ~128, +32sigma)

// ---------------- threefry2x32 (exact JAX partitionable implementation) ----------------
// rotl via v_alignbit_b32: rotl(v,r) == rotr(v,32-r) == alignbit(v,v,32-r)
__device__ __forceinline__ uint32_t rotl32(uint32_t v, uint32_t r){
  return __builtin_amdgcn_alignbit(v, v, 32u - r);
}

__device__ __forceinline__ void tf2x32(uint32_t k0, uint32_t k1, uint32_t x0, uint32_t x1,
                                       uint32_t &o0, uint32_t &o1){
  uint32_t k2 = k0 ^ k1 ^ 0x1BD11BDAu;
  x0 += k0; x1 += k1;
#define TFR(r) { x0 += x1; x1 = rotl32(x1,(r)); x1 ^= x0; }
  TFR(13u) TFR(15u) TFR(26u) TFR(6u)   x0 += k1; x1 += k2 + 1u;
  TFR(17u) TFR(29u) TFR(16u) TFR(24u)  x0 += k2; x1 += k0 + 2u;
  TFR(13u) TFR(15u) TFR(26u) TFR(6u)   x0 += k0; x1 += k1 + 3u;
  TFR(17u) TFR(29u) TFR(16u) TFR(24u)  x0 += k1; x1 += k2 + 4u;
  TFR(13u) TFR(15u) TFR(26u) TFR(6u)   x0 += k2; x1 += k0 + 5u;
#undef TFR
  o0 = x0; o1 = x1;
}

// four independent threefry chains (pixels px..px+3), source-interleaved for 4-way ILP.
// identical algebra to tf2x32 with x0=0, x1=px+i; returns o0^o1 per chain.
__device__ __forceinline__ void tf4_quad(
  uint32_t A0, uint32_t A1, uint32_t A2,
  uint32_t B0, uint32_t B1, uint32_t B2,
  uint32_t C0, uint32_t C1, uint32_t C2,
  uint32_t D0, uint32_t D1, uint32_t D2,
  uint32_t px,
  uint32_t &rA, uint32_t &rB, uint32_t &rC, uint32_t &rD)
{
  uint32_t a0 = A0, a1 = px + A1;
  uint32_t b0 = B0, b1 = (px + 1u) + B1;
  uint32_t c0 = C0, c1 = (px + 2u) + C1;
  uint32_t d0 = D0, d1 = (px + 3u) + D1;
#define R4(r) { a0 += a1; b0 += b1; c0 += c1; d0 += d1;                       \
  a1 = rotl32(a1,(r)); b1 = rotl32(b1,(r)); c1 = rotl32(c1,(r)); d1 = rotl32(d1,(r)); \
  a1 ^= a0; b1 ^= b0; c1 ^= c0; d1 ^= d0; }
#define INJ4(KA,KB,KC,KD, JA,JB,JC,JD, i) {                                   \
  a0 += (KA); b0 += (KB); c0 += (KC); d0 += (KD);                             \
  a1 += (JA) + (i); b1 += (JB) + (i); c1 += (JC) + (i); d1 += (JD) + (i); }
  R4(13u) R4(15u) R4(26u) R4(6u)
  INJ4(A1,B1,C1,D1, A2,B2,C2,D2, 1u)
  R4(17u) R4(29u) R4(16u) R4(24u)
  INJ4(A2,B2,C2,D2, A0,B0,C0,D0, 2u)
  R4(13u) R4(15u) R4(26u) R4(6u)
  INJ4(A0,B0,C0,D0, A1,B1,C1,D1, 3u)
  R4(17u) R4(29u) R4(16u) R4(24u)
  INJ4(A1,B1,C1,D1, A2,B2,C2,D2, 4u)
  R4(13u) R4(15u) R4(26u) R4(6u)
  INJ4(A2,B2,C2,D2, A0,B0,C0,D0, 5u)
#undef R4
#undef INJ4
  rA = a0 ^ a1; rB = b0 ^ b1; rC = c0 ^ c1; rD = d0 ^ d1;
}

// pack score+index so that u64 max == (higher score, then lower index)
__device__ __forceinline__ unsigned long long packCand(uint32_t bits, uint32_t pix){
  float f = __uint_as_float((bits >> 9) | 0x3f800000u) - 1.0f;  // jax uniform [0,1)
  uint32_t u = __float_as_uint(f) ^ 0x80000000u;                // monotone map (f>=0)
  return ((unsigned long long)u << 32) | (unsigned long long)(0xFFFFFFFFu - pix);
}

// sorted-descending 10-element list, sentinel 0
__device__ __forceinline__ void t10_insert(unsigned long long* l, unsigned long long c){
  if (c > l[9]) {
    l[9] = c;
#pragma unroll
    for (int i = 9; i > 0; --i){
      unsigned long long a = l[i-1], b2 = l[i];
      if (b2 > a){ l[i-1] = b2; l[i] = a; }
    }
  }
}

// ---- single fused kernel (best verified configuration, R12) ----
// pass1 (8-deep batched loads): read x -> u8 in LDS + hist (no global stores).
// Threshold (wave-0 shuffle). Deferred IGN fill (drains under scoring).
// 4-way-ILP threefry scoring from LDS. Wave-parallel top-10. Dilated patches.
__global__ __launch_bounds__(1024)
void apm_kernel(const float* __restrict__ x, int* __restrict__ out){
  const int b = blockIdx.x;
  const int tid = threadIdx.x;
  const float* img = x + (size_t)b * NPIX;
  int* outb = out + (size_t)b * NPIX;

  __shared__ uint32_t u8img[16384];         // 64 KB: packed u8 image (4 px/word)
  __shared__ uint32_t histR[1024];          // 256 bins x 4 lane-columns (conflict spread)
  __shared__ float csum[256], cvsum[256];
  __shared__ uint32_t s_kw[4];
  __shared__ unsigned long long buf[2][CAP];
  __shared__ int s_cnt[2], s_fail[2], s_np[2];
  __shared__ int s_qthr, s_nroi;
  __shared__ unsigned long long s_top[2][64][10];
  __shared__ unsigned long long s_top2[2][8][10];
  __shared__ int s_pr[2][10], s_pc[2][10];

  histR[tid] = 0u;
  if (tid < 2){
    uint32_t o0, o1;
    tf2x32(0u, 1u, 0u, (uint32_t)(2*b + tid), o0, o1);
    s_kw[2*tid] = o0; s_kw[2*tid+1] = o1;
    s_cnt[tid] = 0;
  }
  __syncthreads();

  // ---- pass 1: 8-deep batched float4 loads (MLP), u8->LDS, histogram (no gl stores) ----
  {
    const float4* x4 = (const float4*)img;
    const uint32_t c4 = (uint32_t)(tid & 3);
#define PROC(V, K) {                                                          \
      uint32_t u0 = (uint32_t)min(max((int)floorf((V).x*255.0f),0),255);      \
      uint32_t u1 = (uint32_t)min(max((int)floorf((V).y*255.0f),0),255);      \
      uint32_t u2 = (uint32_t)min(max((int)floorf((V).z*255.0f),0),255);      \
      uint32_t u3 = (uint32_t)min(max((int)floorf((V).w*255.0f),0),255);      \
      u8img[tid + 1024*(K)] = u0 | (u1<<8) | (u2<<16) | (u3<<24);             \
      atomicAdd(&histR[(u0<<2)|c4],1u); atomicAdd(&histR[(u1<<2)|c4],1u);     \
      atomicAdd(&histR[(u2<<2)|c4],1u); atomicAdd(&histR[(u3<<2)|c4],1u); }
    for (int kk = 0; kk < 2; ++kk){         // 2 x 8 x 1024 = 16384 float4 = 65536 px
      int base = 8*kk;
      float4 v0 = x4[tid + 1024*(base+0)];
      float4 v1 = x4[tid + 1024*(base+1)];
      float4 v2 = x4[tid + 1024*(base+2)];
      float4 v3 = x4[tid + 1024*(base+3)];
      float4 v4 = x4[tid + 1024*(base+4)];
      float4 v5 = x4[tid + 1024*(base+5)];
      float4 v6 = x4[tid + 1024*(base+6)];
      float4 v7 = x4[tid + 1024*(base+7)];
      PROC(v0, base+0) PROC(v1, base+1) PROC(v2, base+2) PROC(v3, base+3)
      PROC(v4, base+4) PROC(v5, base+5) PROC(v6, base+6) PROC(v7, base+7)
    }
#undef PROC
  }
  __syncthreads();

  // ---- threshold: wave 0 only, shuffle-based (verified R7-R12 structure) ----
  // exactness: all partial sums are integers < 2^24 -> fp32 adds in any order
  // are bit-identical to jnp.cumsum.
  if (tid < 64){
    const int lane = tid;
    const int4* hv = (const int4*)&histR[16*lane];  // bins 4lane..4lane+3, 4 cols each
    int4 p0 = hv[0], p1 = hv[1], p2 = hv[2], p3 = hv[3];
    int h0 = p0.x + p0.y + p0.z + p0.w;
    int h1 = p1.x + p1.y + p1.z + p1.w;
    int h2 = p2.x + p2.y + p2.z + p2.w;
    int h3 = p3.x + p3.y + p3.z + p3.w;
    int cand = 256;
    if (h3) cand = 4*lane + 3;
    if (h2) cand = 4*lane + 2;
    if (h1) cand = 4*lane + 1;
    if (h0) cand = 4*lane + 0;
    for (int off = 32; off; off >>= 1) cand = min(cand, __shfl_xor(cand, off));
    const float img_min = (float)cand;
    float c0 = (float)h0, c1 = c0 + h1, c2 = c1 + h2, c3 = c2 + h3;
    float bv = 4.0f*lane - img_min;
    float v0 = h0*bv;
    float v1 = v0 + h1*(bv + 1.0f);
    float v2 = v1 + h2*(bv + 2.0f);
    float v3 = v2 + h3*(bv + 3.0f);
    float cc = c3, vv = v3;
    for (int off = 1; off < 64; off <<= 1){
      float a = __shfl_up(cc, off), b2 = __shfl_up(vv, off);
      if (lane >= off){ cc += a; vv += b2; }
    }
    const float cexc = cc - c3, vexc = vv - v3;
    const float cs0 = cexc+c0, cs1 = cexc+c1, cs2 = cexc+c2, cs3 = cexc+c3;
    const float vs0 = vexc+v0, vs1 = vexc+v1, vs2 = vexc+v2, vs3 = vexc+v3;
    csum[4*lane]   = cs0; csum[4*lane+1]  = cs1;
    csum[4*lane+2] = cs2; csum[4*lane+3]  = cs3;
    cvsum[4*lane]   = vs0; cvsum[4*lane+1] = vs1;
    cvsum[4*lane+2] = vs2; cvsum[4*lane+3] = vs3;
    const float ctot = __shfl(cc, 63), vtot = __shfl(vv, 63);
    const float s_tot_o = vtot + img_min * ctot;
    unsigned long long best = 0ull;
#define OTSU_BIN(CS, VS, J)                                              \
    { int bin = 4*lane + (J);                                            \
      if (bin < 255){                                                    \
        float w0_ = (CS);                                                \
        float w1_ = 65536.0f - w0_;                                      \
        float cs = (VS) + img_min * (CS);                                \
        float m0 = cs / fmaxf(w0_, 1e-12f);                              \
        float m1 = (s_tot_o - cs) / fmaxf(w1_, 1e-12f);                  \
        float d = m0 - m1;                                               \
        float vb = (w0_*w1_) * (d*d);                                    \
        unsigned long long pk =                                          \
          ((unsigned long long)__float_as_uint(vb) << 32) |              \
           (unsigned long long)(255 - bin);                              \
        if (pk > best) best = pk;                                        \
      } }
    OTSU_BIN(cs0, vs0, 0) OTSU_BIN(cs1, vs1, 1)
    OTSU_BIN(cs2, vs2, 2) OTSU_BIN(cs3, vs3, 3)
#undef OTSU_BIN
    for (int off = 32; off; off >>= 1){
      unsigned int hi = (unsigned int)(best >> 32), lo = (unsigned int)best;
      unsigned int hio = (unsigned int)__shfl_xor((int)hi, off);
      unsigned int loo = (unsigned int)__shfl_xor((int)lo, off);
      unsigned long long ob = ((unsigned long long)hio << 32) | loo;
      if (ob > best) best = ob;
    }
    if (lane == 0){
      int bestIdx = 255 - (int)(best & 0xFFFFFFFFull);
      float otsu = fminf(fmaxf((float)bestIdx, 1.0f), 254.0f);
      float n_tot = ctot, s_tot = vtot;
      float t_curr = otsu - img_min, t_prev = t_curr + 10.0f;
      int it = 0;
      while (fabsf(t_curr - t_prev) > 0.5f && it < 64){
        int idx = min(max((int)floorf(t_curr + img_min), 0), 255);
        float n_back = csum[idx], s_back = cvsum[idx];
        float n_fore = n_tot - n_back, s_fore = s_tot - s_back;
        float mean_back = (n_back > 0.0f) ? (s_back / fmaxf(n_back, 1.0f)) : 0.0f;
        float mean_fore = s_fore / fmaxf(n_fore, 1.0f);
        float t_next = (mean_back - mean_fore) /
                       (logf(fmaxf(mean_back, 1e-12f)) - logf(fmaxf(mean_fore, 1e-12f)));
        if (mean_back < 1e-12f) t_next = mean_fore * 0.5f;
        t_prev = t_curr; t_curr = t_next; ++it;
      }
      float lit = t_curr + img_min;
      // integer threshold: for integer q, (float)q > lit <=> q >= floor(lit)+1
      // NaN lit (degenerate image): predicate false for all q -> qthr=256
      int qthr;
      if (!(lit == lit)) qthr = 256;
      else               qthr = (int)floorf(lit) + 1;
      s_qthr = qthr;
      int nlo = (qthr <= 0) ? 0 : (int)csum[min(qthr, 256) - 1];
      s_nroi = NPIX - nlo;             // exact count(q > lit)
    }
  }
  __syncthreads();

  // ---- deferred IGN fill: posted stores drain under the scoring phase below ----
  {
    int4* o4 = (int4*)outb;
    const int4 f4 = make_int4(IGN, IGN, IGN, IGN);
#pragma unroll
    for (int k = 0; k < 16; ++k) o4[tid + 1024*k] = f4;
  }

  // ---- scoring: u8 from LDS, 4 independent threefry chains per word (4-way ILP) ----
  const int qthr = s_qthr;
  const uint32_t fk0 = s_kw[0], fk1 = s_kw[1], bk0 = s_kw[2], bk1 = s_kw[3];
  const uint32_t fk2 = fk0 ^ fk1 ^ 0x1BD11BDAu;
  const uint32_t bk2 = bk0 ^ bk1 ^ 0x1BD11BDAu;
  const int4* u4 = (const int4*)u8img;      // LDS packed u8 as int4 (16 px each)
  for (int k = 0; k < 4; ++k){              // runtime loop: body I$-resident
    int4 w = u4[tid + 1024*k];
    uint32_t pw0 = (uint32_t)(16*(tid + 1024*k));
#pragma unroll
    for (int m = 0; m < 4; ++m){
      uint32_t pk = (m==0)?(uint32_t)w.x:(m==1)?(uint32_t)w.y:(m==2)?(uint32_t)w.z:(uint32_t)w.w;
      uint32_t pb = pw0 + (uint32_t)(4*m);
      bool r0 = ((int)( pk        & 255u) >= qthr);
      bool r1 = ((int)((pk >>  8) & 255u) >= qthr);
      bool r2 = ((int)((pk >> 16) & 255u) >= qthr);
      bool r3 = ((int)( pk >> 24        ) >= qthr);
      uint32_t bA, bB, bC, bD;
      tf4_quad(r0?fk0:bk0, r0?fk1:bk1, r0?fk2:bk2,
               r1?fk0:bk0, r1?fk1:bk1, r1?fk2:bk2,
               r2?fk0:bk0, r2?fk1:bk1, r2?fk2:bk2,
               r3?fk0:bk0, r3?fk1:bk1, r3?fk2:bk2,
               pb, bA, bB, bC, bD);
#define HIT(BITS, RR, PIX) if ((BITS) >= 0xFF000000u){                        \
        int r2_ = (RR) ? 0 : 1;                                               \
        int idx = atomicAdd(&s_cnt[r2_], 1);                                  \
        if (idx < CAP) buf[r2_][idx] = packCand((BITS), (PIX)); }
      HIT(bA, r0, pb)
      HIT(bB, r1, pb + 1u)
      HIT(bC, r2, pb + 2u)
      HIT(bD, r3, pb + 3u)
#undef HIT
    }
  }
  __syncthreads();

  // ---- validity: need (collected >= 10) or (collected == region size); no overflow ----
  if (tid < 2){
    int rs = tid ? (NPIX - s_nroi) : s_nroi;
    int cc = s_cnt[tid];
    s_fail[tid] = (cc > CAP) || (cc < 10 && cc != rs);
  }
  __syncthreads();

  // ---- per-lane top-10 (wave 0 -> fg, wave 1 -> bg); fallback rescans LDS u8 ----
  const int wv = tid >> 6, lane = tid & 63;
  if (wv < 2){
    const int r2 = wv;
    unsigned long long t[10];
#pragma unroll
    for (int i = 0; i < 10; ++i) t[i] = 0ull;
    if (!s_fail[r2]){
      int n = min(s_cnt[r2], CAP);
      for (int i = lane; i < n; i += 64) t10_insert(t, buf[r2][i]);
    } else {
      const uint32_t kk0 = s_kw[2*r2], kk1 = s_kw[2*r2+1];
      for (int k = 0; k < 1024; ++k){
        uint32_t pix = (uint32_t)(lane + 64*k);
        int q = (int)((u8img[pix >> 2] >> (8*(pix & 3u))) & 255u);
        bool r = (q >= qthr);
        if (r == (r2 == 0)){
          uint32_t o0, o1; tf2x32(kk0, kk1, 0u, pix, o0, o1);
          t10_insert(t, packCand(o0 ^ o1, pix));
        }
      }
    }
#pragma unroll
    for (int i = 0; i < 10; ++i) s_top[r2][lane][i] = t[i];
  }
  __syncthreads();
  // ---- merge 64 -> 8 ----
  if (wv < 2 && lane < 8){
    unsigned long long t[10];
#pragma unroll
    for (int i = 0; i < 10; ++i) t[i] = 0ull;
    for (int l2 = 0; l2 < 8; ++l2)
#pragma unroll
      for (int i = 0; i < 10; ++i) t10_insert(t, s_top[wv][lane*8 + l2][i]);
#pragma unroll
    for (int i = 0; i < 10; ++i) s_top2[wv][lane][i] = t[i];
  }
  __syncthreads();
  // ---- merge 8 -> 1, extract points ----
  if (wv < 2 && lane == 0){
    unsigned long long t[10];
#pragma unroll
    for (int i = 0; i < 10; ++i) t[i] = 0ull;
    for (int l2 = 0; l2 < 8; ++l2)
#pragma unroll
      for (int i = 0; i < 10; ++i) t10_insert(t, s_top2[wv][l2][i]);
    int np = 0;
    for (int i = 0; i < 10; ++i){
      if (t[i]){
        uint32_t pix = 0xFFFFFFFFu - (uint32_t)(t[i] & 0xFFFFFFFFull);
        s_pr[wv][np] = (int)(pix >> 8);
        s_pc[wv][np] = (int)(pix & 255u);
        ++np;
      }
    }
    s_np[wv] = np;
  }
  __syncthreads();

  // ---- write dilated seed patches (<=180 px); duplicates write identical values ----
  const int nfg = s_np[0], nbg = s_np[1];
  const int npts = nfg + nbg;
  if (tid < npts*9){
    int k = tid / 9, d = tid - k*9;
    int pr = (k < nfg) ? s_pr[0][k] : s_pr[1][k - nfg];
    int pc = (k < nfg) ? s_pc[0][k] : s_pc[1][k - nfg];
    pr += d/3 - 1; pc += d%3 - 1;
    if (pr >= 0 && pr < 256 && pc >= 0 && pc < 256){
      bool fgd = false, bgd = false;
      for (int i = 0; i < nfg; ++i) fgd |= (abs(pr - s_pr[0][i]) <= 1) && (abs(pc - s_pc[0][i]) <= 1);
      for (int i = 0; i < nbg; ++i) bgd |= (abs(pr - s_pr[1][i]) <= 1) && (abs(pc - s_pc[1][i]) <= 1);
      int val = (fgd && bgd) ? IGN : (fgd ? 1 : 0);
      outb[pr*256 + pc] = val;
    }
  }
}

extern "C" void kernel_launch(void* const* d_in, const int* in_sizes, int n_in,
                              void* d_out, int out_size, void* d_ws, size_t ws_size,
                              hipStream_t stream) {
  const float* x = (const float*)d_in[0];
  int* out = (int*)d_out;
  int B = in_sizes[0] / NPIX;
  apm_kernel<<<B, 1024, 0, stream>>>(x, out);
}